// Round 1
// baseline (390.489 us; speedup 1.0000x reference)
//
#include <hip/hip_runtime.h>

typedef __attribute__((ext_vector_type(8))) __bf16 bf16x8;
typedef __attribute__((ext_vector_type(4))) __bf16 bf16x4;
typedef __attribute__((ext_vector_type(4))) float f32x4;

constexpr int kB = 8, kN = 8192, kE = 65536;
constexpr int kBN = kB * kN;    // 65536 nodes total
constexpr int kBE = kB * kE;    // 524288 edges total
constexpr int kDN = 64, kDE = 64, kIU = 128;

constexpr int XS = 200;  // X row stride in bf16 (192 + 8 pad)
constexpr int HS = 136;  // H row stride (128 + 8)
constexpr int ES = 72;   // E row stride (64 + 8)

// ---------------------------------------------------------------------------
// Fused edge-MLP: gather -> relu(x@W_in+b) -> relu(h@W_out+b) -> e_new
//   e_new -> atomic segment-sum into sums/counts (ws)
//   relu(e_new@W_edge+b) -> edges_out (global)
// One 256-thread block processes 64 edges per tile; grid-stride over tiles.
// Wave w owns output columns [32w,32w+32) of layer1 and [16w,16w+16) of
// layers 2/3; weight B-fragments live in registers for the whole kernel.
// ---------------------------------------------------------------------------
__global__ __launch_bounds__(256, 2)
void edge_mlp_kernel(const float* __restrict__ nodes,
                     const float* __restrict__ edges,
                     const int* __restrict__ senders,
                     const int* __restrict__ receivers,
                     const float* __restrict__ W_in,
                     const float* __restrict__ b_in,
                     const float* __restrict__ W_out,
                     const float* __restrict__ b_out,
                     const float* __restrict__ W_edge,
                     const float* __restrict__ b_edge,
                     float* __restrict__ edges_out,
                     float* __restrict__ sums,
                     float* __restrict__ counts)
{
    __shared__ alignas(16) __bf16 Xs_[64 * XS];
    __shared__ alignas(16) __bf16 Hs_[64 * HS];
    __shared__ alignas(16) __bf16 Es_[64 * ES];
    __shared__ int rgS[64];   // receiver gather row (flat node table)
    __shared__ int sgS[64];   // sender gather row
    __shared__ int rsS[64];   // receiver scatter row (-1 = drop)

    const int tid  = threadIdx.x;
    const int lane = tid & 63;
    const int wave = tid >> 6;
    const int c16  = lane & 15;   // MFMA n / m index
    const int q    = lane >> 4;   // MFMA quad

    // ---- preload weight B-fragments: elem j -> W[k0 + q*8 + j][n0 + c16] ----
    bf16x8 winf[6][2];
#pragma unroll
    for (int kk = 0; kk < 6; ++kk)
#pragma unroll
        for (int nt = 0; nt < 2; ++nt)
#pragma unroll
            for (int j = 0; j < 8; ++j)
                winf[kk][nt][j] =
                    (__bf16)W_in[(kk * 32 + q * 8 + j) * kIU + wave * 32 + nt * 16 + c16];

    bf16x8 woutf[4];
#pragma unroll
    for (int kk = 0; kk < 4; ++kk)
#pragma unroll
        for (int j = 0; j < 8; ++j)
            woutf[kk][j] =
                (__bf16)W_out[(kk * 32 + q * 8 + j) * kDN + wave * 16 + c16];

    bf16x8 wedgef[2];
#pragma unroll
    for (int kk = 0; kk < 2; ++kk)
#pragma unroll
        for (int j = 0; j < 8; ++j)
            wedgef[kk][j] =
                (__bf16)W_edge[(kk * 32 + q * 8 + j) * kDE + wave * 16 + c16];

    const float bin0 = b_in[wave * 32 + c16];
    const float bin1 = b_in[wave * 32 + 16 + c16];
    const float bo   = b_out[wave * 16 + c16];
    const float beg  = b_edge[wave * 16 + c16];

    const int ntiles = kBE / 64;  // 8192
    for (int t = blockIdx.x; t < ntiles; t += gridDim.x) {
        __syncthreads();  // protect idx/X/E buffers from previous iteration
        const int g0 = t * 64;

        // ---- stage indices (+ counts atomic, one per edge) ----
        if (tid < 64) {
            const int g = g0 + tid;
            const int b = g >> 16;         // g / E
            const int r = receivers[g];
            const int s = senders[g];
            const int roff = r + (b << 13);
            const int soff = s + (b << 13);
            rgS[tid] = (r < 0) ? (kBN - 1) : roff;   // jnp -1 wraps to last row
            sgS[tid] = (s < 0) ? (kBN - 1) : soff;
            const int rs = (r < 0) ? -1 : roff;      // segment_sum drops negatives
            rsS[tid] = rs;
            if (rs >= 0) atomicAdd(&counts[rs], 1.0f);
        }
        __syncthreads();

        // ---- stage X = [recv || edge || send] as bf16 (4 threads per row) ----
        {
            const int row = tid >> 2;
            const int qt  = tid & 3;
            const float4* nrec = (const float4*)nodes + (size_t)rgS[row] * 16;
            const float4* nsnd = (const float4*)nodes + (size_t)sgS[row] * 16;
            const float4* erow = (const float4*)edges + (size_t)(g0 + row) * 16;
            __bf16* xr = &Xs_[row * XS];
#pragma unroll
            for (int i = 0; i < 4; ++i) {
                const int c = qt * 16 + i * 4;
                float4 a = nrec[qt * 4 + i];
                float4 e = erow[qt * 4 + i];
                float4 s = nsnd[qt * 4 + i];
                bf16x4 pa = {(__bf16)a.x, (__bf16)a.y, (__bf16)a.z, (__bf16)a.w};
                bf16x4 pe = {(__bf16)e.x, (__bf16)e.y, (__bf16)e.z, (__bf16)e.w};
                bf16x4 ps = {(__bf16)s.x, (__bf16)s.y, (__bf16)s.z, (__bf16)s.w};
                *(bf16x4*)&xr[c]       = pa;
                *(bf16x4*)&xr[64 + c]  = pe;
                *(bf16x4*)&xr[128 + c] = ps;
            }
        }
        __syncthreads();

        // ---- layer 1: [64x192] @ [192x128] -> H ----
        f32x4 acc1[4][2];
#pragma unroll
        for (int m = 0; m < 4; ++m) {
            acc1[m][0] = (f32x4){0.f, 0.f, 0.f, 0.f};
            acc1[m][1] = (f32x4){0.f, 0.f, 0.f, 0.f};
        }
#pragma unroll
        for (int m = 0; m < 4; ++m) {
            const __bf16* ar = &Xs_[(m * 16 + c16) * XS + q * 8];
            bf16x8 a[6];
#pragma unroll
            for (int kk = 0; kk < 6; ++kk) a[kk] = *(const bf16x8*)(ar + kk * 32);
#pragma unroll
            for (int nt = 0; nt < 2; ++nt)
#pragma unroll
                for (int kk = 0; kk < 6; ++kk)
                    acc1[m][nt] = __builtin_amdgcn_mfma_f32_16x16x32_bf16(
                        a[kk], winf[kk][nt], acc1[m][nt], 0, 0, 0);
        }
        // bias+relu -> H (C/D layout: row = q*4+r, col = c16)
#pragma unroll
        for (int m = 0; m < 4; ++m)
#pragma unroll
            for (int nt = 0; nt < 2; ++nt)
#pragma unroll
                for (int r = 0; r < 4; ++r) {
                    float v = acc1[m][nt][r] + (nt ? bin1 : bin0);
                    v = fmaxf(v, 0.f);
                    Hs_[(m * 16 + q * 4 + r) * HS + wave * 32 + nt * 16 + c16] = (__bf16)v;
                }
        __syncthreads();

        // ---- layer 2: [64x128] @ [128x64] -> E (e_new) ----
        f32x4 acc2[4];
#pragma unroll
        for (int m = 0; m < 4; ++m) acc2[m] = (f32x4){0.f, 0.f, 0.f, 0.f};
#pragma unroll
        for (int m = 0; m < 4; ++m) {
            const __bf16* ar = &Hs_[(m * 16 + c16) * HS + q * 8];
            bf16x8 a[4];
#pragma unroll
            for (int kk = 0; kk < 4; ++kk) a[kk] = *(const bf16x8*)(ar + kk * 32);
#pragma unroll
            for (int kk = 0; kk < 4; ++kk)
                acc2[m] = __builtin_amdgcn_mfma_f32_16x16x32_bf16(
                    a[kk], woutf[kk], acc2[m], 0, 0, 0);
        }
#pragma unroll
        for (int m = 0; m < 4; ++m)
#pragma unroll
            for (int r = 0; r < 4; ++r) {
                float v = fmaxf(acc2[m][r] + bo, 0.f);
                Es_[(m * 16 + q * 4 + r) * ES + wave * 16 + c16] = (__bf16)v;
            }
        __syncthreads();

        // ---- layer 3: [64x64] @ [64x64] -> edges_out ----
#pragma unroll
        for (int m = 0; m < 4; ++m) {
            const __bf16* ar = &Es_[(m * 16 + c16) * ES + q * 8];
            bf16x8 a0 = *(const bf16x8*)ar;
            bf16x8 a1 = *(const bf16x8*)(ar + 32);
            f32x4 acc3 = (f32x4){0.f, 0.f, 0.f, 0.f};
            acc3 = __builtin_amdgcn_mfma_f32_16x16x32_bf16(a0, wedgef[0], acc3, 0, 0, 0);
            acc3 = __builtin_amdgcn_mfma_f32_16x16x32_bf16(a1, wedgef[1], acc3, 0, 0, 0);
#pragma unroll
            for (int r = 0; r < 4; ++r) {
                float v = fmaxf(acc3[r] + beg, 0.f);
                edges_out[(size_t)(g0 + m * 16 + q * 4 + r) * kDE + wave * 16 + c16] = v;
            }
        }

        // ---- scatter e_new into sums (one row per wave per iter: 64 lanes
        //      cover the row's 64 cols -> 256B coalesced atomic segment) ----
#pragma unroll
        for (int i = 0; i < 16; ++i) {
            const int row = i * 4 + wave;
            const int rs = rsS[row];
            if (rs >= 0) {
                float v = (float)Es_[row * ES + lane];
                atomicAdd(&sums[(size_t)rs * kDN + lane], v);
            }
        }
    }
}

// ---------------------------------------------------------------------------
// nodes_new = counts>0 ? sums/counts : 0 ; plus float-cast copies of
// s_flat / r_flat into the output tail.
// ---------------------------------------------------------------------------
__global__ __launch_bounds__(256)
void finalize_kernel(const float* __restrict__ sums,
                     const float* __restrict__ counts,
                     const int* __restrict__ senders,
                     const int* __restrict__ receivers,
                     float* __restrict__ out)
{
    constexpr int NQ = kBN * kDN / 4;  // 1048576 float4s of nodes_new
    const int t = blockIdx.x * blockDim.x + threadIdx.x;
    if (t < NQ) {
        float4 s = ((const float4*)sums)[t];
        const float c = counts[t >> 4];
        float4 o;
        if (c > 0.f) {
            const float inv = 1.f / c;
            o.x = s.x * inv; o.y = s.y * inv; o.z = s.z * inv; o.w = s.w * inv;
        } else {
            o.x = o.y = o.z = o.w = 0.f;
        }
        ((float4*)out)[t] = o;
    } else {
        const int ci = t - NQ;                     // [0, 2*BE)
        constexpr int base = kBN * kDN + kBE * kDE;
        if (ci < kBE) out[base + ci] = (float)senders[ci];
        else          out[base + ci] = (float)receivers[ci - kBE];
    }
}

extern "C" void kernel_launch(void* const* d_in, const int* in_sizes, int n_in,
                              void* d_out, int out_size, void* d_ws, size_t ws_size,
                              hipStream_t stream) {
    const float* nodes     = (const float*)d_in[0];
    const float* edges     = (const float*)d_in[1];
    const int*   senders   = (const int*)d_in[2];
    const int*   receivers = (const int*)d_in[3];
    const float* W_in      = (const float*)d_in[4];
    const float* b_in      = (const float*)d_in[5];
    const float* W_out     = (const float*)d_in[6];
    const float* b_out     = (const float*)d_in[7];
    const float* W_edge    = (const float*)d_in[8];
    const float* b_edge    = (const float*)d_in[9];

    float* out    = (float*)d_out;
    float* sums   = (float*)d_ws;                      // kBN*kDN floats
    float* counts = sums + (size_t)kBN * kDN;          // kBN floats

    hipMemsetAsync(d_ws, 0, (size_t)(kBN * kDN + kBN) * sizeof(float), stream);

    edge_mlp_kernel<<<2048, 256, 0, stream>>>(
        nodes, edges, senders, receivers,
        W_in, b_in, W_out, b_out, W_edge, b_edge,
        out + (size_t)kBN * kDN,   // edges_out region
        sums, counts);

    constexpr int total = kBN * kDN / 4 + 2 * kBE;     // 2097152
    finalize_kernel<<<total / 256, 256, 0, stream>>>(
        sums, counts, senders, receivers, out);
}